// Round 5
// baseline (262.857 us; speedup 1.0000x reference)
//
#include <hip/hip_runtime.h>

// B=8, C=256, Cp=32, N=4096.
// o[b,c,m] = gamma * sum_n h[b,c,n] * softmax_n(f^T g)[n,m] + x[b,c,m]
// R5: XOR-swizzled P (conflict-free), -Mhat folded into MFMA C-init,
// barrier-early 3-buffer pipeline, tiled h layout [b][nt][c][64],
// producer h repacked through LDS -> fully coalesced stores.

typedef __attribute__((ext_vector_type(8))) short bf16x8;    // 8 bf16
typedef __attribute__((ext_vector_type(4))) float f32x4;
typedef __attribute__((ext_vector_type(4))) unsigned short us4;

#define LOG2E 1.44269504088896f

static __device__ __forceinline__ unsigned short f2bf(float x) {
    union { float f; unsigned u; } v; v.f = x;
    unsigned r = v.u + 0x7FFFu + ((v.u >> 16) & 1u);   // RNE
    return (unsigned short)(r >> 16);
}
static __device__ __forceinline__ float bf2f(unsigned short u) {
    union { unsigned u; float f; } v; v.u = ((unsigned)u) << 16;
    return v.f;
}

// ------------------------------------------------ weight convert (fp32->bf16)
__global__ __launch_bounds__(256) void wconv_kernel(
    const float* __restrict__ Wq, const float* __restrict__ Wk,
    const float* __restrict__ Wv, unsigned short* __restrict__ wq,
    unsigned short* __restrict__ wk, unsigned short* __restrict__ wv)
{
    const int i = blockIdx.x * 256 + threadIdx.x;   // 320 blocks -> 81920
    if (i < 8192)            wq[i] = f2bf(Wq[i] * LOG2E);
    else if (i < 16384)      wk[i - 8192] = f2bf(Wk[i - 8192]);
    else                     wv[i - 16384] = f2bf(Wv[i - 16384]);
}

// --------------------------------------------------- fused f,g,h producer
// Block = 256 thr (4 waves) handles (b, 64 n). x[c][n] -> LDS [n][c] bf16,
// MFMA for h (c-split across waves) and f,g (n-slice per wave).
// h goes D-layout -> LDS [c][72] -> coalesced 16B stores into tiled layout
// h_bf[b][nt][c][64].
#define XPITCH 264
#define HPITCH 72
__global__ __launch_bounds__(256, 2) void producer_kernel(
    const float* __restrict__ x, const unsigned short* __restrict__ wq,
    const unsigned short* __restrict__ wk, const unsigned short* __restrict__ wv,
    unsigned short* __restrict__ f_t, unsigned short* __restrict__ g_t,
    unsigned short* __restrict__ h_bf, float* __restrict__ normg,
    unsigned* __restrict__ maxnf_u)
{
    __shared__ unsigned short xh_s[256 * HPITCH];   // 36.9 KB: x stage, then h repack
    __shared__ unsigned short fg_s[4 * 2 * 512];    // per-wave f,g repack, 8 KB

    const int tid  = threadIdx.x;
    const int w    = tid >> 6;
    const int lane = tid & 63;
    const int q    = lane >> 4;
    const int r    = lane & 15;
    const int b    = blockIdx.y;
    const int nt   = blockIdx.x;
    const int n0   = nt << 6;
    const size_t bN = (size_t)b << 12;
    const f32x4 zero = {0.f, 0.f, 0.f, 0.f};

    // ---- stage x tile (transpose fp32 [c][n] -> bf16 LDS [n][c=XPITCH]) ---
#pragma unroll
    for (int jj = 0; jj < 4; jj++) {
        const int task = jj * 256 + tid;       // 1024 tasks: (c-quad, n-quad)
        const int n4 = task & 15;
        const int c4 = task >> 4;
        float va[4][4];
#pragma unroll
        for (int i = 0; i < 4; i++) {
            const float4 v = ((const float4*)(x + ((size_t)b << 20)
                              + (size_t)(c4 * 4 + i) * 4096 + n0))[n4];
            va[i][0] = v.x; va[i][1] = v.y; va[i][2] = v.z; va[i][3] = v.w;
        }
#pragma unroll
        for (int i = 0; i < 4; i++) {
            us4 t;
            t.x = f2bf(va[0][i]); t.y = f2bf(va[1][i]);
            t.z = f2bf(va[2][i]); t.w = f2bf(va[3][i]);
            *(us4*)(xh_s + (n4 * 4 + i) * XPITCH + c4 * 4) = t;
        }
    }
    __syncthreads();

    // ---- MFMA: h (4 cs x 4 ns), f,g (2 ms each, ns == w) ------------------
    f32x4 acch[4][4];
    f32x4 accf[2], accg[2];
#pragma unroll
    for (int cs = 0; cs < 4; cs++)
#pragma unroll
        for (int ns = 0; ns < 4; ns++) acch[cs][ns] = zero;
    accf[0] = accf[1] = accg[0] = accg[1] = zero;

    for (int ks = 0; ks < 8; ks++) {
        const int kof = ks * 32 + q * 8;
        bf16x8 av[4], aq[2], ak[2];
#pragma unroll
        for (int cs = 0; cs < 4; cs++)
            av[cs] = *(const bf16x8*)(wv + (size_t)(w * 64 + cs * 16 + r) * 256 + kof);
#pragma unroll
        for (int ms = 0; ms < 2; ms++) {
            aq[ms] = *(const bf16x8*)(wq + (size_t)(ms * 16 + r) * 256 + kof);
            ak[ms] = *(const bf16x8*)(wk + (size_t)(ms * 16 + r) * 256 + kof);
        }
#pragma unroll
        for (int ns = 0; ns < 4; ns++) {
            const bf16x8 bx = *(const bf16x8*)(xh_s + (ns * 16 + r) * XPITCH + kof);
#pragma unroll
            for (int cs = 0; cs < 4; cs++)
                acch[cs][ns] = __builtin_amdgcn_mfma_f32_16x16x32_bf16(av[cs], bx, acch[cs][ns], 0, 0, 0);
            if (ns == w) {
#pragma unroll
                for (int ms = 0; ms < 2; ms++) {
                    accf[ms] = __builtin_amdgcn_mfma_f32_16x16x32_bf16(aq[ms], bx, accf[ms], 0, 0, 0);
                    accg[ms] = __builtin_amdgcn_mfma_f32_16x16x32_bf16(ak[ms], bx, accg[ms], 0, 0, 0);
                }
            }
        }
    }

    // ---- f,g: relu+bf16 -> per-wave LDS [n(16)][c'(32)] -> vector store ---
    unsigned short* lf = fg_s + w * 1024;
    unsigned short* lg = lf + 512;
#pragma unroll
    for (int ms = 0; ms < 2; ms++)
#pragma unroll
        for (int reg = 0; reg < 4; reg++) {
            lf[r * 32 + ms * 16 + q * 4 + reg] = f2bf(fmaxf(accf[ms][reg], 0.f));
            lg[r * 32 + ms * 16 + q * 4 + reg] = f2bf(fmaxf(accg[ms][reg], 0.f));
        }
    // wave-private region: dependency-tracked LDS, no barrier needed
    const bf16x8 ffrag = *(const bf16x8*)(lf + r * 32 + q * 8);
    const bf16x8 gfrag = *(const bf16x8*)(lg + r * 32 + q * 8);
    *(bf16x8*)(f_t + ((bN + n0 + w * 16 + r) << 5) + q * 8) = ffrag;
    *(bf16x8*)(g_t + ((bN + n0 + w * 16 + r) << 5) + q * 8) = gfrag;

    float nf2 = 0.f, ng2 = 0.f;
#pragma unroll
    for (int i = 0; i < 8; i++) {
        const float fv = bf2f(((unsigned short*)&ffrag)[i]);
        const float gv = bf2f(((unsigned short*)&gfrag)[i]);
        nf2 += fv * fv; ng2 += gv * gv;
    }
    nf2 += __shfl_xor(nf2, 16); nf2 += __shfl_xor(nf2, 32);
    ng2 += __shfl_xor(ng2, 16); ng2 += __shfl_xor(ng2, 32);
    if (q == 0) normg[bN + n0 + w * 16 + r] = sqrtf(ng2);
    float nf = sqrtf(nf2);
#pragma unroll
    for (int off = 1; off < 16; off <<= 1) nf = fmaxf(nf, __shfl_xor(nf, off));
    if (lane == 0) atomicMax(maxnf_u + b, __float_as_uint(nf));

    // ---- h: D-layout -> LDS [c][HPITCH] -> coalesced tiled store ----------
    __syncthreads();   // all xh_s (x-stage) reads done
#pragma unroll
    for (int cs = 0; cs < 4; cs++)
#pragma unroll
        for (int ns = 0; ns < 4; ns++)
#pragma unroll
            for (int reg = 0; reg < 4; reg++)
                xh_s[(w * 64 + cs * 16 + q * 4 + reg) * HPITCH + ns * 16 + r] =
                    f2bf(fmaxf(acch[cs][ns][reg], 0.f));
    __syncthreads();
    const size_t hdst = ((size_t)(b * 64 + nt)) << 14;   // *256*64 elements
#pragma unroll
    for (int p = 0; p < 8; p++) {
        const int c = p * 32 + (tid >> 3);
        const int k = tid & 7;
        *(bf16x8*)(h_bf + hdst + c * 64 + k * 8) =
            *(const bf16x8*)(xh_s + c * HPITCH + k * 8);
    }
}

// ------------------------------------------------------- MFMA attention
// Block = 256 thr (4 waves), (b, 64 m-cols). Single pass over n, deferred
// normalization; -Mhat folded into S-MFMA C-init; XOR-swizzled P buffers
// (3-slot rotation, one barrier/iter, produce(t+1) then PV(t)).
__global__ __launch_bounds__(256, 2) void attn_kernel(
    const unsigned short* __restrict__ f_t, const unsigned short* __restrict__ g_t,
    const unsigned short* __restrict__ h_bf, const float* __restrict__ x,
    const float* __restrict__ gamma, const float* __restrict__ normg,
    const unsigned* __restrict__ maxnf_u, float* __restrict__ out)
{
    __shared__ unsigned short p_s[3][64 * 64];   // [slot][m][n], XOR-swizzled
    __shared__ float red_l[4][64];
    __shared__ float sLi[64];

    const int tid  = threadIdx.x;
    const int w    = tid >> 6;
    const int lane = tid & 63;
    const int q    = lane >> 4;
    const int r    = lane & 15;
    const int b    = blockIdx.y;
    const int m0   = blockIdx.x << 6;

    const size_t bN = (size_t)b << 12;
    const int c0 = w << 6;
    const f32x4 zero = {0.f, 0.f, 0.f, 0.f};

    bf16x8 bg[4];
    float nMh[4];                 // negative upper-bound max (exp2 domain)
    const float mnf = __uint_as_float(maxnf_u[b]);
#pragma unroll
    for (int ms = 0; ms < 4; ms++) {
        bg[ms] = *(const bf16x8*)(g_t + ((bN + m0 + ms * 16 + r) << 5) + (q << 3));
        nMh[ms] = -(mnf * normg[bN + m0 + ms * 16 + r] * 1.0002f);
    }

    f32x4 acc[4][4];
#pragma unroll
    for (int cs = 0; cs < 4; cs++)
#pragma unroll
        for (int ms = 0; ms < 4; ms++) acc[cs][ms] = zero;
    float lt[4] = {0.f, 0.f, 0.f, 0.f};

    // XOR-swizzle offsets (16B chunks, key = m&7 = r&7)
    const int wkey = r & 7;
    const int wchunkoff = (((((w << 1) + (q >> 1)) ^ wkey) << 3)) + ((q & 1) << 2);
    const int rkoff0 = ((q ^ wkey) << 3);          // ch=0 chunk = q
    const int rkoff1 = (((4 + q) ^ wkey) << 3);    // ch=1 chunk = 4+q

    auto ldf = [&](int t) {
        return *(const bf16x8*)(f_t + ((bN + (t << 6) + (w << 4) + r) << 5) + (q << 3));
    };
    auto produce = [&](const bf16x8 af, unsigned short* pb) {
#pragma unroll
        for (int ms = 0; ms < 4; ms++) {
            f32x4 ci; ci[0] = ci[1] = ci[2] = ci[3] = nMh[ms];
            const f32x4 sv = __builtin_amdgcn_mfma_f32_16x16x32_bf16(af, bg[ms], ci, 0, 0, 0);
            const float e0 = __builtin_amdgcn_exp2f(sv[0]);
            const float e1 = __builtin_amdgcn_exp2f(sv[1]);
            const float e2 = __builtin_amdgcn_exp2f(sv[2]);
            const float e3 = __builtin_amdgcn_exp2f(sv[3]);
            lt[ms] += (e0 + e1) + (e2 + e3);
            uint2 pk;
            pk.x = __builtin_amdgcn_perm(__float_as_uint(e1), __float_as_uint(e0), 0x07060302u);
            pk.y = __builtin_amdgcn_perm(__float_as_uint(e3), __float_as_uint(e2), 0x07060302u);
            *(uint2*)(pb + ((ms * 16 + r) << 6) + wchunkoff) = pk;
        }
    };

    bf16x8 afn = ldf(0);
    produce(afn, p_s[0]);
    afn = ldf(1);

    int sr = 0, sw = 1;
    for (int t = 0; t < 64; t++) {
        __syncthreads();
        // h A-fragments for PV(t) — issued early, drain under produce VALU
        const unsigned short* hb = h_bf + (((size_t)(b * 64 + t)) << 14);
        bf16x8 ah[8];
#pragma unroll
        for (int cs = 0; cs < 4; cs++) {
            const unsigned short* hp = hb + ((c0 + cs * 16 + r) << 6) + (q << 3);
            ah[cs * 2]     = *(const bf16x8*)(hp);
            ah[cs * 2 + 1] = *(const bf16x8*)(hp + 32);
        }
        if (t < 63) {
            const bf16x8 afc = afn;
            if (t < 62) afn = ldf(t + 2);
            produce(afc, p_s[sw]);
        }
        const unsigned short* pb = p_s[sr];
        bf16x8 bp[4][2];
#pragma unroll
        for (int ms = 0; ms < 4; ms++) {
            bp[ms][0] = *(const bf16x8*)(pb + ((ms * 16 + r) << 6) + rkoff0);
            bp[ms][1] = *(const bf16x8*)(pb + ((ms * 16 + r) << 6) + rkoff1);
        }
#pragma unroll
        for (int ch = 0; ch < 2; ch++)
#pragma unroll
            for (int cs = 0; cs < 4; cs++)
#pragma unroll
                for (int ms = 0; ms < 4; ms++)
                    acc[cs][ms] = __builtin_amdgcn_mfma_f32_16x16x32_bf16(
                        ah[cs * 2 + ch], bp[ms][ch], acc[cs][ms], 0, 0, 0);
        sr = sw;
        sw = (sw == 2) ? 0 : sw + 1;
    }

    // ---------------- L reduction ------------------------------------------
#pragma unroll
    for (int ms = 0; ms < 4; ms++) {
        lt[ms] += __shfl_xor(lt[ms], 16);
        lt[ms] += __shfl_xor(lt[ms], 32);
    }
    __syncthreads();
    if (q == 0)
#pragma unroll
        for (int ms = 0; ms < 4; ms++) red_l[w][ms * 16 + r] = lt[ms];
    __syncthreads();
    if (tid < 64)
        sLi[tid] = 1.f / (red_l[0][tid] + red_l[1][tid] + red_l[2][tid] + red_l[3][tid]);
    __syncthreads();

    // ---------------- epilogue: (gamma/L) * O + x --------------------------
    const float gm = gamma[0];
#pragma unroll
    for (int cs = 0; cs < 4; cs++) {
#pragma unroll
        for (int ms = 0; ms < 4; ms++) {
            const float gl = gm * sLi[ms * 16 + r];
#pragma unroll
            for (int reg = 0; reg < 4; reg++) {
                const int c = c0 + cs * 16 + q * 4 + reg;
                const size_t a = (((size_t)b * 256 + c) << 12) + m0 + ms * 16 + r;
                out[a] = gl * acc[cs][ms][reg] + x[a];
            }
        }
    }
}

// ------------------------------------------------------------------- launch
extern "C" void kernel_launch(void* const* d_in, const int* in_sizes, int n_in,
                              void* d_out, int out_size, void* d_ws, size_t ws_size,
                              hipStream_t stream) {
    const float* x     = (const float*)d_in[0];
    const float* Wq    = (const float*)d_in[1];
    const float* Wk    = (const float*)d_in[2];
    const float* Wv    = (const float*)d_in[3];
    const float* gamma = (const float*)d_in[4];
    float* out = (float*)d_out;

    char* ws = (char*)d_ws;
    unsigned short* f_t  = (unsigned short*)ws;                        // 2 MB
    unsigned short* g_t  = (unsigned short*)(ws + (2u << 20));         // 2 MB
    unsigned short* h_bf = (unsigned short*)(ws + (4u << 20));         // 16 MB
    float*          ng   = (float*)(ws + (20u << 20));                 // 128 KB
    unsigned*       mnf  = (unsigned*)(ws + (20u << 20) + (1u << 17)); // 32 B
    unsigned short* wq   = (unsigned short*)(ws + (21u << 20));        // 16 KB
    unsigned short* wk   = wq + 8192;                                  // 16 KB
    unsigned short* wv   = wk + 8192;                                  // 128 KB

    hipMemsetAsync(mnf, 0, 8 * sizeof(unsigned), stream);
    wconv_kernel<<<dim3(320), 256, 0, stream>>>(Wq, Wk, Wv, wq, wk, wv);
    producer_kernel<<<dim3(64, 8), 256, 0, stream>>>(x, wq, wk, wv, f_t, g_t, h_bf, ng, mnf);
    attn_kernel<<<dim3(64, 8), 256, 0, stream>>>(f_t, g_t, h_bf, x, gamma, ng, mnf, out);
}

// Round 7
// 250.637 us; speedup vs baseline: 1.0488x; 1.0488x over previous
//
#include <hip/hip_runtime.h>

// B=8, C=256, Cp=32, N=4096.
// o[b,c,m] = gamma * sum_n h[b,c,n] * softmax_n(f^T g)[n,m] + x[b,c,m]
// R6b: compile fix (nontemporal load needs ext_vector type, not float4).
// R6: no atomics (pmax partial-max array, reduced in attn prologue),
// XCD-pinned grids (b = blockIdx.x & 7 -> h/f/g L2-resident per XCD),
// nontemporal x/out streams. Core MFMA structure from R5.

typedef __attribute__((ext_vector_type(8))) short bf16x8;    // 8 bf16
typedef __attribute__((ext_vector_type(4))) float f32x4;
typedef __attribute__((ext_vector_type(4))) unsigned short us4;

#define LOG2E 1.44269504088896f

static __device__ __forceinline__ unsigned short f2bf(float x) {
    union { float f; unsigned u; } v; v.f = x;
    unsigned r = v.u + 0x7FFFu + ((v.u >> 16) & 1u);   // RNE
    return (unsigned short)(r >> 16);
}
static __device__ __forceinline__ float bf2f(unsigned short u) {
    union { unsigned u; float f; } v; v.u = ((unsigned)u) << 16;
    return v.f;
}

// ------------------------------------------------ weight convert (fp32->bf16)
__global__ __launch_bounds__(256) void wconv_kernel(
    const float* __restrict__ Wq, const float* __restrict__ Wk,
    const float* __restrict__ Wv, unsigned short* __restrict__ wq,
    unsigned short* __restrict__ wk, unsigned short* __restrict__ wv)
{
    const int i = blockIdx.x * 256 + threadIdx.x;   // 320 blocks -> 81920
    if (i < 8192)            wq[i] = f2bf(Wq[i] * LOG2E);
    else if (i < 16384)      wk[i - 8192] = f2bf(Wk[i - 8192]);
    else                     wv[i - 16384] = f2bf(Wv[i - 16384]);
}

// --------------------------------------------------- fused f,g,h producer
// 1D grid 512: b = id&7 (XCD pin), nt = id>>3. Block handles (b, 64 n).
// x[c][n] -> LDS [n][c] bf16, MFMA for h (c-split across waves) and f,g
// (n-slice per wave). h repacked via LDS -> tiled h_bf[b][nt][c][64].
// Per-wave ||f||-max partials -> pmax[b*256 + nt*4 + w] (NO atomics).
#define XPITCH 264
#define HPITCH 72
__global__ __launch_bounds__(256, 2) void producer_kernel(
    const float* __restrict__ x, const unsigned short* __restrict__ wq,
    const unsigned short* __restrict__ wk, const unsigned short* __restrict__ wv,
    unsigned short* __restrict__ f_t, unsigned short* __restrict__ g_t,
    unsigned short* __restrict__ h_bf, float* __restrict__ normg,
    float* __restrict__ pmax)
{
    __shared__ unsigned short xh_s[256 * HPITCH];   // 36.9 KB: x stage, then h repack
    __shared__ unsigned short fg_s[4 * 2 * 512];    // per-wave f,g repack, 8 KB

    const int tid  = threadIdx.x;
    const int w    = tid >> 6;
    const int lane = tid & 63;
    const int q    = lane >> 4;
    const int r    = lane & 15;
    const int b    = blockIdx.x & 7;     // XCD pin
    const int nt   = blockIdx.x >> 3;
    const int n0   = nt << 6;
    const size_t bN = (size_t)b << 12;
    const f32x4 zero = {0.f, 0.f, 0.f, 0.f};

    // ---- stage x tile (transpose fp32 [c][n] -> bf16 LDS [n][c=XPITCH]) ---
#pragma unroll
    for (int jj = 0; jj < 4; jj++) {
        const int task = jj * 256 + tid;       // 1024 tasks: (c-quad, n-quad)
        const int n4 = task & 15;
        const int c4 = task >> 4;
        float va[4][4];
#pragma unroll
        for (int i = 0; i < 4; i++) {
            const f32x4 v = __builtin_nontemporal_load(
                (const f32x4*)(x + ((size_t)b << 20)
                               + (size_t)(c4 * 4 + i) * 4096 + n0) + n4);
            va[i][0] = v.x; va[i][1] = v.y; va[i][2] = v.z; va[i][3] = v.w;
        }
#pragma unroll
        for (int i = 0; i < 4; i++) {
            us4 t;
            t.x = f2bf(va[0][i]); t.y = f2bf(va[1][i]);
            t.z = f2bf(va[2][i]); t.w = f2bf(va[3][i]);
            *(us4*)(xh_s + (n4 * 4 + i) * XPITCH + c4 * 4) = t;
        }
    }
    __syncthreads();

    // ---- MFMA: h (4 cs x 4 ns), f,g (2 ms each, ns == w) ------------------
    f32x4 acch[4][4];
    f32x4 accf[2], accg[2];
#pragma unroll
    for (int cs = 0; cs < 4; cs++)
#pragma unroll
        for (int ns = 0; ns < 4; ns++) acch[cs][ns] = zero;
    accf[0] = accf[1] = accg[0] = accg[1] = zero;

    for (int ks = 0; ks < 8; ks++) {
        const int kof = ks * 32 + q * 8;
        bf16x8 av[4], aq[2], ak[2];
#pragma unroll
        for (int cs = 0; cs < 4; cs++)
            av[cs] = *(const bf16x8*)(wv + (size_t)(w * 64 + cs * 16 + r) * 256 + kof);
#pragma unroll
        for (int ms = 0; ms < 2; ms++) {
            aq[ms] = *(const bf16x8*)(wq + (size_t)(ms * 16 + r) * 256 + kof);
            ak[ms] = *(const bf16x8*)(wk + (size_t)(ms * 16 + r) * 256 + kof);
        }
#pragma unroll
        for (int ns = 0; ns < 4; ns++) {
            const bf16x8 bx = *(const bf16x8*)(xh_s + (ns * 16 + r) * XPITCH + kof);
#pragma unroll
            for (int cs = 0; cs < 4; cs++)
                acch[cs][ns] = __builtin_amdgcn_mfma_f32_16x16x32_bf16(av[cs], bx, acch[cs][ns], 0, 0, 0);
            if (ns == w) {
#pragma unroll
                for (int ms = 0; ms < 2; ms++) {
                    accf[ms] = __builtin_amdgcn_mfma_f32_16x16x32_bf16(aq[ms], bx, accf[ms], 0, 0, 0);
                    accg[ms] = __builtin_amdgcn_mfma_f32_16x16x32_bf16(ak[ms], bx, accg[ms], 0, 0, 0);
                }
            }
        }
    }

    // ---- f,g: relu+bf16 -> per-wave LDS [n(16)][c'(32)] -> vector store ---
    unsigned short* lf = fg_s + w * 1024;
    unsigned short* lg = lf + 512;
#pragma unroll
    for (int ms = 0; ms < 2; ms++)
#pragma unroll
        for (int reg = 0; reg < 4; reg++) {
            lf[r * 32 + ms * 16 + q * 4 + reg] = f2bf(fmaxf(accf[ms][reg], 0.f));
            lg[r * 32 + ms * 16 + q * 4 + reg] = f2bf(fmaxf(accg[ms][reg], 0.f));
        }
    // wave-private region: dependency-tracked LDS, no barrier needed
    const bf16x8 ffrag = *(const bf16x8*)(lf + r * 32 + q * 8);
    const bf16x8 gfrag = *(const bf16x8*)(lg + r * 32 + q * 8);
    *(bf16x8*)(f_t + ((bN + n0 + w * 16 + r) << 5) + q * 8) = ffrag;
    *(bf16x8*)(g_t + ((bN + n0 + w * 16 + r) << 5) + q * 8) = gfrag;

    float nf2 = 0.f, ng2 = 0.f;
#pragma unroll
    for (int i = 0; i < 8; i++) {
        const float fv = bf2f(((unsigned short*)&ffrag)[i]);
        const float gv = bf2f(((unsigned short*)&gfrag)[i]);
        nf2 += fv * fv; ng2 += gv * gv;
    }
    nf2 += __shfl_xor(nf2, 16); nf2 += __shfl_xor(nf2, 32);
    ng2 += __shfl_xor(ng2, 16); ng2 += __shfl_xor(ng2, 32);
    if (q == 0) normg[bN + n0 + w * 16 + r] = sqrtf(ng2);
    float nf = sqrtf(nf2);
#pragma unroll
    for (int off = 1; off < 16; off <<= 1) nf = fmaxf(nf, __shfl_xor(nf, off));
    if (lane == 0) pmax[(b << 8) + nt * 4 + w] = nf;   // plain store, no atomic

    // ---- h: D-layout -> LDS [c][HPITCH] -> coalesced tiled store ----------
    __syncthreads();   // all xh_s (x-stage) reads done
#pragma unroll
    for (int cs = 0; cs < 4; cs++)
#pragma unroll
        for (int ns = 0; ns < 4; ns++)
#pragma unroll
            for (int reg = 0; reg < 4; reg++)
                xh_s[(w * 64 + cs * 16 + q * 4 + reg) * HPITCH + ns * 16 + r] =
                    f2bf(fmaxf(acch[cs][ns][reg], 0.f));
    __syncthreads();
    const size_t hdst = ((size_t)(b * 64 + nt)) << 14;   // *256*64 elements
#pragma unroll
    for (int p = 0; p < 8; p++) {
        const int c = p * 32 + (tid >> 3);
        const int k = tid & 7;
        *(bf16x8*)(h_bf + hdst + c * 64 + k * 8) =
            *(const bf16x8*)(xh_s + c * HPITCH + k * 8);
    }
}

// ------------------------------------------------------- MFMA attention
// 1D grid 512: b = id&7 (same XCD pin as producer -> h/f/g L2-resident),
// m-tile = (id>>3)*64. Single pass over n, deferred normalization;
// -Mhat in S-MFMA C-init; XOR-swizzled 3-slot P pipeline.
__global__ __launch_bounds__(256, 2) void attn_kernel(
    const unsigned short* __restrict__ f_t, const unsigned short* __restrict__ g_t,
    const unsigned short* __restrict__ h_bf, const float* __restrict__ x,
    const float* __restrict__ gamma, const float* __restrict__ normg,
    const float* __restrict__ pmax, float* __restrict__ out)
{
    __shared__ unsigned short p_s[3][64 * 64];   // [slot][m][n], XOR-swizzled
    __shared__ float red_l[4][64];
    __shared__ float sLi[64];

    const int tid  = threadIdx.x;
    const int w    = tid >> 6;
    const int lane = tid & 63;
    const int q    = lane >> 4;
    const int r    = lane & 15;
    const int b    = blockIdx.x & 7;          // XCD pin
    const int m0   = (blockIdx.x >> 3) << 6;

    const size_t bN = (size_t)b << 12;
    const int c0 = w << 6;

    // reduce per-wave f-norm partials (256 floats, L2-hit) -> mnf
    float pv = pmax[(b << 8) + lane];
    pv = fmaxf(pv, pmax[(b << 8) + 64 + lane]);
    pv = fmaxf(pv, pmax[(b << 8) + 128 + lane]);
    pv = fmaxf(pv, pmax[(b << 8) + 192 + lane]);
#pragma unroll
    for (int off = 1; off < 64; off <<= 1) pv = fmaxf(pv, __shfl_xor(pv, off));
    const float mnf = pv;

    bf16x8 bg[4];
    float nMh[4];                 // negative upper-bound max (exp2 domain)
#pragma unroll
    for (int ms = 0; ms < 4; ms++) {
        bg[ms] = *(const bf16x8*)(g_t + ((bN + m0 + ms * 16 + r) << 5) + (q << 3));
        nMh[ms] = -(mnf * normg[bN + m0 + ms * 16 + r] * 1.0002f);
    }

    f32x4 acc[4][4];
    const f32x4 zero = {0.f, 0.f, 0.f, 0.f};
#pragma unroll
    for (int cs = 0; cs < 4; cs++)
#pragma unroll
        for (int ms = 0; ms < 4; ms++) acc[cs][ms] = zero;
    float lt[4] = {0.f, 0.f, 0.f, 0.f};

    // XOR-swizzle offsets (16B chunks, key = m&7 = r&7)
    const int wkey = r & 7;
    const int wchunkoff = (((((w << 1) + (q >> 1)) ^ wkey) << 3)) + ((q & 1) << 2);
    const int rkoff0 = ((q ^ wkey) << 3);          // ch=0 chunk = q
    const int rkoff1 = (((4 + q) ^ wkey) << 3);    // ch=1 chunk = 4+q

    auto ldf = [&](int t) {
        return *(const bf16x8*)(f_t + ((bN + (t << 6) + (w << 4) + r) << 5) + (q << 3));
    };
    auto produce = [&](const bf16x8 af, unsigned short* pb) {
#pragma unroll
        for (int ms = 0; ms < 4; ms++) {
            f32x4 ci; ci[0] = ci[1] = ci[2] = ci[3] = nMh[ms];
            const f32x4 sv = __builtin_amdgcn_mfma_f32_16x16x32_bf16(af, bg[ms], ci, 0, 0, 0);
            const float e0 = __builtin_amdgcn_exp2f(sv[0]);
            const float e1 = __builtin_amdgcn_exp2f(sv[1]);
            const float e2 = __builtin_amdgcn_exp2f(sv[2]);
            const float e3 = __builtin_amdgcn_exp2f(sv[3]);
            lt[ms] += (e0 + e1) + (e2 + e3);
            uint2 pk;
            pk.x = __builtin_amdgcn_perm(__float_as_uint(e1), __float_as_uint(e0), 0x07060302u);
            pk.y = __builtin_amdgcn_perm(__float_as_uint(e3), __float_as_uint(e2), 0x07060302u);
            *(uint2*)(pb + ((ms * 16 + r) << 6) + wchunkoff) = pk;
        }
    };

    bf16x8 afn = ldf(0);
    produce(afn, p_s[0]);
    afn = ldf(1);

    int sr = 0, sw = 1;
    for (int t = 0; t < 64; t++) {
        __syncthreads();
        // h A-fragments for PV(t) — issued early, drain under produce VALU
        const unsigned short* hb = h_bf + (((size_t)(b * 64 + t)) << 14);
        bf16x8 ah[8];
#pragma unroll
        for (int cs = 0; cs < 4; cs++) {
            const unsigned short* hp = hb + ((c0 + cs * 16 + r) << 6) + (q << 3);
            ah[cs * 2]     = *(const bf16x8*)(hp);
            ah[cs * 2 + 1] = *(const bf16x8*)(hp + 32);
        }
        if (t < 63) {
            const bf16x8 afc = afn;
            if (t < 62) afn = ldf(t + 2);
            produce(afc, p_s[sw]);
        }
        const unsigned short* pb = p_s[sr];
        bf16x8 bp[4][2];
#pragma unroll
        for (int ms = 0; ms < 4; ms++) {
            bp[ms][0] = *(const bf16x8*)(pb + ((ms * 16 + r) << 6) + rkoff0);
            bp[ms][1] = *(const bf16x8*)(pb + ((ms * 16 + r) << 6) + rkoff1);
        }
#pragma unroll
        for (int ch = 0; ch < 2; ch++)
#pragma unroll
            for (int cs = 0; cs < 4; cs++)
#pragma unroll
                for (int ms = 0; ms < 4; ms++)
                    acc[cs][ms] = __builtin_amdgcn_mfma_f32_16x16x32_bf16(
                        ah[cs * 2 + ch], bp[ms][ch], acc[cs][ms], 0, 0, 0);
        sr = sw;
        sw = (sw == 2) ? 0 : sw + 1;
    }

    // ---------------- L reduction ------------------------------------------
#pragma unroll
    for (int ms = 0; ms < 4; ms++) {
        lt[ms] += __shfl_xor(lt[ms], 16);
        lt[ms] += __shfl_xor(lt[ms], 32);
    }
    __syncthreads();
    if (q == 0)
#pragma unroll
        for (int ms = 0; ms < 4; ms++) red_l[w][ms * 16 + r] = lt[ms];
    __syncthreads();
    if (tid < 64)
        sLi[tid] = 1.f / (red_l[0][tid] + red_l[1][tid] + red_l[2][tid] + red_l[3][tid]);
    __syncthreads();

    // ---------------- epilogue: (gamma/L) * O + x (nontemporal) ------------
    const float gm = gamma[0];
#pragma unroll
    for (int cs = 0; cs < 4; cs++) {
#pragma unroll
        for (int ms = 0; ms < 4; ms++) {
            const float gl = gm * sLi[ms * 16 + r];
#pragma unroll
            for (int reg = 0; reg < 4; reg++) {
                const int c = c0 + cs * 16 + q * 4 + reg;
                const size_t a = (((size_t)b * 256 + c) << 12) + m0 + ms * 16 + r;
                const float xv = __builtin_nontemporal_load(x + a);
                __builtin_nontemporal_store(gl * acc[cs][ms][reg] + xv, out + a);
            }
        }
    }
}

// ------------------------------------------------------------------- launch
extern "C" void kernel_launch(void* const* d_in, const int* in_sizes, int n_in,
                              void* d_out, int out_size, void* d_ws, size_t ws_size,
                              hipStream_t stream) {
    const float* x     = (const float*)d_in[0];
    const float* Wq    = (const float*)d_in[1];
    const float* Wk    = (const float*)d_in[2];
    const float* Wv    = (const float*)d_in[3];
    const float* gamma = (const float*)d_in[4];
    float* out = (float*)d_out;

    char* ws = (char*)d_ws;
    unsigned short* f_t  = (unsigned short*)ws;                        // 2 MB
    unsigned short* g_t  = (unsigned short*)(ws + (2u << 20));         // 2 MB
    unsigned short* h_bf = (unsigned short*)(ws + (4u << 20));         // 16 MB
    float*          ng   = (float*)(ws + (20u << 20));                 // 128 KB
    float*          pmx  = (float*)(ws + (20u << 20) + (1u << 17));    // 8 KB
    unsigned short* wq   = (unsigned short*)(ws + (21u << 20));        // 16 KB
    unsigned short* wk   = wq + 8192;                                  // 16 KB
    unsigned short* wv   = wk + 8192;                                  // 128 KB

    wconv_kernel<<<dim3(320), 256, 0, stream>>>(Wq, Wk, Wv, wq, wk, wv);
    producer_kernel<<<dim3(512), 256, 0, stream>>>(x, wq, wk, wv, f_t, g_t, h_bf, ng, pmx);
    attn_kernel<<<dim3(512), 256, 0, stream>>>(f_t, g_t, h_bf, x, gamma, ng, pmx, out);
}

// Round 8
// 249.508 us; speedup vs baseline: 1.0535x; 1.0045x over previous
//
#include <hip/hip_runtime.h>

// B=8, C=256, Cp=32, N=4096.
// o[b,c,m] = gamma * sum_n h[b,c,n] * softmax_n(f^T g)[n,m] + x[b,c,m]
// R8: attn rebuilt for occupancy: 512 thr / 8 waves, 32-AGPR acc per wave
// (c-split 32), n-tile 128, __launch_bounds__(512,4) -> <=128 regs ->
// 4 waves/SIMD (50% occ). Producer/wconv identical to R7.

typedef __attribute__((ext_vector_type(8))) short bf16x8;    // 8 bf16
typedef __attribute__((ext_vector_type(4))) float f32x4;
typedef __attribute__((ext_vector_type(4))) unsigned short us4;

#define LOG2E 1.44269504088896f

static __device__ __forceinline__ unsigned short f2bf(float x) {
    union { float f; unsigned u; } v; v.f = x;
    unsigned r = v.u + 0x7FFFu + ((v.u >> 16) & 1u);   // RNE
    return (unsigned short)(r >> 16);
}
static __device__ __forceinline__ float bf2f(unsigned short u) {
    union { unsigned u; float f; } v; v.u = ((unsigned)u) << 16;
    return v.f;
}

// ------------------------------------------------ weight convert (fp32->bf16)
__global__ __launch_bounds__(256) void wconv_kernel(
    const float* __restrict__ Wq, const float* __restrict__ Wk,
    const float* __restrict__ Wv, unsigned short* __restrict__ wq,
    unsigned short* __restrict__ wk, unsigned short* __restrict__ wv)
{
    const int i = blockIdx.x * 256 + threadIdx.x;   // 320 blocks -> 81920
    if (i < 8192)            wq[i] = f2bf(Wq[i] * LOG2E);
    else if (i < 16384)      wk[i - 8192] = f2bf(Wk[i - 8192]);
    else                     wv[i - 16384] = f2bf(Wv[i - 16384]);
}

// --------------------------------------------------- fused f,g,h producer
// (identical to R7)
#define XPITCH 264
#define HPITCH 72
__global__ __launch_bounds__(256, 2) void producer_kernel(
    const float* __restrict__ x, const unsigned short* __restrict__ wq,
    const unsigned short* __restrict__ wk, const unsigned short* __restrict__ wv,
    unsigned short* __restrict__ f_t, unsigned short* __restrict__ g_t,
    unsigned short* __restrict__ h_bf, float* __restrict__ normg,
    float* __restrict__ pmax)
{
    __shared__ unsigned short xh_s[256 * HPITCH];   // 36.9 KB
    __shared__ unsigned short fg_s[4 * 2 * 512];    // 8 KB

    const int tid  = threadIdx.x;
    const int w    = tid >> 6;
    const int lane = tid & 63;
    const int q    = lane >> 4;
    const int r    = lane & 15;
    const int b    = blockIdx.x & 7;     // XCD pin
    const int nt   = blockIdx.x >> 3;
    const int n0   = nt << 6;
    const size_t bN = (size_t)b << 12;
    const f32x4 zero = {0.f, 0.f, 0.f, 0.f};

#pragma unroll
    for (int jj = 0; jj < 4; jj++) {
        const int task = jj * 256 + tid;
        const int n4 = task & 15;
        const int c4 = task >> 4;
        float va[4][4];
#pragma unroll
        for (int i = 0; i < 4; i++) {
            const f32x4 v = __builtin_nontemporal_load(
                (const f32x4*)(x + ((size_t)b << 20)
                               + (size_t)(c4 * 4 + i) * 4096 + n0) + n4);
            va[i][0] = v.x; va[i][1] = v.y; va[i][2] = v.z; va[i][3] = v.w;
        }
#pragma unroll
        for (int i = 0; i < 4; i++) {
            us4 t;
            t.x = f2bf(va[0][i]); t.y = f2bf(va[1][i]);
            t.z = f2bf(va[2][i]); t.w = f2bf(va[3][i]);
            *(us4*)(xh_s + (n4 * 4 + i) * XPITCH + c4 * 4) = t;
        }
    }
    __syncthreads();

    f32x4 acch[4][4];
    f32x4 accf[2], accg[2];
#pragma unroll
    for (int cs = 0; cs < 4; cs++)
#pragma unroll
        for (int ns = 0; ns < 4; ns++) acch[cs][ns] = zero;
    accf[0] = accf[1] = accg[0] = accg[1] = zero;

    for (int ks = 0; ks < 8; ks++) {
        const int kof = ks * 32 + q * 8;
        bf16x8 av[4], aq[2], ak[2];
#pragma unroll
        for (int cs = 0; cs < 4; cs++)
            av[cs] = *(const bf16x8*)(wv + (size_t)(w * 64 + cs * 16 + r) * 256 + kof);
#pragma unroll
        for (int ms = 0; ms < 2; ms++) {
            aq[ms] = *(const bf16x8*)(wq + (size_t)(ms * 16 + r) * 256 + kof);
            ak[ms] = *(const bf16x8*)(wk + (size_t)(ms * 16 + r) * 256 + kof);
        }
#pragma unroll
        for (int ns = 0; ns < 4; ns++) {
            const bf16x8 bx = *(const bf16x8*)(xh_s + (ns * 16 + r) * XPITCH + kof);
#pragma unroll
            for (int cs = 0; cs < 4; cs++)
                acch[cs][ns] = __builtin_amdgcn_mfma_f32_16x16x32_bf16(av[cs], bx, acch[cs][ns], 0, 0, 0);
            if (ns == w) {
#pragma unroll
                for (int ms = 0; ms < 2; ms++) {
                    accf[ms] = __builtin_amdgcn_mfma_f32_16x16x32_bf16(aq[ms], bx, accf[ms], 0, 0, 0);
                    accg[ms] = __builtin_amdgcn_mfma_f32_16x16x32_bf16(ak[ms], bx, accg[ms], 0, 0, 0);
                }
            }
        }
    }

    unsigned short* lf = fg_s + w * 1024;
    unsigned short* lg = lf + 512;
#pragma unroll
    for (int ms = 0; ms < 2; ms++)
#pragma unroll
        for (int reg = 0; reg < 4; reg++) {
            lf[r * 32 + ms * 16 + q * 4 + reg] = f2bf(fmaxf(accf[ms][reg], 0.f));
            lg[r * 32 + ms * 16 + q * 4 + reg] = f2bf(fmaxf(accg[ms][reg], 0.f));
        }
    const bf16x8 ffrag = *(const bf16x8*)(lf + r * 32 + q * 8);
    const bf16x8 gfrag = *(const bf16x8*)(lg + r * 32 + q * 8);
    *(bf16x8*)(f_t + ((bN + n0 + w * 16 + r) << 5) + q * 8) = ffrag;
    *(bf16x8*)(g_t + ((bN + n0 + w * 16 + r) << 5) + q * 8) = gfrag;

    float nf2 = 0.f, ng2 = 0.f;
#pragma unroll
    for (int i = 0; i < 8; i++) {
        const float fv = bf2f(((unsigned short*)&ffrag)[i]);
        const float gv = bf2f(((unsigned short*)&gfrag)[i]);
        nf2 += fv * fv; ng2 += gv * gv;
    }
    nf2 += __shfl_xor(nf2, 16); nf2 += __shfl_xor(nf2, 32);
    ng2 += __shfl_xor(ng2, 16); ng2 += __shfl_xor(ng2, 32);
    if (q == 0) normg[bN + n0 + w * 16 + r] = sqrtf(ng2);
    float nf = sqrtf(nf2);
#pragma unroll
    for (int off = 1; off < 16; off <<= 1) nf = fmaxf(nf, __shfl_xor(nf, off));
    if (lane == 0) pmax[(b << 8) + nt * 4 + w] = nf;

    __syncthreads();
#pragma unroll
    for (int cs = 0; cs < 4; cs++)
#pragma unroll
        for (int ns = 0; ns < 4; ns++)
#pragma unroll
            for (int reg = 0; reg < 4; reg++)
                xh_s[(w * 64 + cs * 16 + q * 4 + reg) * HPITCH + ns * 16 + r] =
                    f2bf(fmaxf(acch[cs][ns][reg], 0.f));
    __syncthreads();
    const size_t hdst = ((size_t)(b * 64 + nt)) << 14;
#pragma unroll
    for (int p = 0; p < 8; p++) {
        const int c = p * 32 + (tid >> 3);
        const int k = tid & 7;
        *(bf16x8*)(h_bf + hdst + c * 64 + k * 8) =
            *(const bf16x8*)(xh_s + c * HPITCH + k * 8);
    }
}

// ------------------------------------------------------- MFMA attention
// 512 thr / 8 waves. Wave w: c-range [w*32, w*32+32), produces 16 n-rows of
// the 128-n P tile. acc[2][4] = 32 AGPR/wave -> <=128 total regs ->
// 4 waves/SIMD (2 blocks/CU, 50% occ). 3-slot XOR-swizzled P, 1 barrier/iter.
__global__ __launch_bounds__(512, 4) void attn_kernel(
    const unsigned short* __restrict__ f_t, const unsigned short* __restrict__ g_t,
    const unsigned short* __restrict__ h_bf, const float* __restrict__ x,
    const float* __restrict__ gamma, const float* __restrict__ normg,
    const float* __restrict__ pmax, float* __restrict__ out)
{
    __shared__ unsigned short p_s[3][64 * 128];  // [slot][m][n], XOR-swizzled
    __shared__ float red_l[8][64];
    __shared__ float sLi[64];

    const int tid  = threadIdx.x;
    const int w    = tid >> 6;      // wave 0..7
    const int lane = tid & 63;
    const int q    = lane >> 4;
    const int r    = lane & 15;
    const int b    = blockIdx.x & 7;          // XCD pin
    const int m0   = (blockIdx.x >> 3) << 6;

    const size_t bN = (size_t)b << 12;
    const int c0 = w << 5;                    // 32 channels per wave

    // reduce per-wave f-norm partials (256 floats, L2-hit) -> mnf
    float pv = pmax[(b << 8) + lane];
    pv = fmaxf(pv, pmax[(b << 8) + 64 + lane]);
    pv = fmaxf(pv, pmax[(b << 8) + 128 + lane]);
    pv = fmaxf(pv, pmax[(b << 8) + 192 + lane]);
#pragma unroll
    for (int off = 1; off < 64; off <<= 1) pv = fmaxf(pv, __shfl_xor(pv, off));
    const float mnf = pv;

    bf16x8 bg[4];
    float nMh[4];
#pragma unroll
    for (int ms = 0; ms < 4; ms++) {
        bg[ms] = *(const bf16x8*)(g_t + ((bN + m0 + ms * 16 + r) << 5) + (q << 3));
        nMh[ms] = -(mnf * normg[bN + m0 + ms * 16 + r] * 1.0002f);
    }

    f32x4 acc[2][4];
    const f32x4 zero = {0.f, 0.f, 0.f, 0.f};
#pragma unroll
    for (int cs = 0; cs < 2; cs++)
#pragma unroll
        for (int ms = 0; ms < 4; ms++) acc[cs][ms] = zero;
    float lt[4] = {0.f, 0.f, 0.f, 0.f};

    // swizzle: 16B chunk idx within a 256B row, phys = (idx&8)|((idx^r)&7)
    const int wchunk = (w << 1) + (q >> 1);                         // write: 0..15
    const int wphys  = (wchunk & 8) | ((wchunk ^ r) & 7);
    const int woff   = (wphys << 3) + ((q & 1) << 2);               // u16 units

    auto ldf = [&](int t) {   // f rows n = t*128 + w*16 + r
        return *(const bf16x8*)(f_t + ((bN + (t << 7) + (w << 4) + r) << 5) + (q << 3));
    };
    auto produce = [&](const bf16x8 af, unsigned short* pb) {
#pragma unroll
        for (int ms = 0; ms < 4; ms++) {
            f32x4 ci; ci[0] = ci[1] = ci[2] = ci[3] = nMh[ms];
            const f32x4 sv = __builtin_amdgcn_mfma_f32_16x16x32_bf16(af, bg[ms], ci, 0, 0, 0);
            const float e0 = __builtin_amdgcn_exp2f(sv[0]);
            const float e1 = __builtin_amdgcn_exp2f(sv[1]);
            const float e2 = __builtin_amdgcn_exp2f(sv[2]);
            const float e3 = __builtin_amdgcn_exp2f(sv[3]);
            lt[ms] += (e0 + e1) + (e2 + e3);
            uint2 pk;
            pk.x = __builtin_amdgcn_perm(__float_as_uint(e1), __float_as_uint(e0), 0x07060302u);
            pk.y = __builtin_amdgcn_perm(__float_as_uint(e3), __float_as_uint(e2), 0x07060302u);
            *(uint2*)(pb + ((ms * 16 + r) << 7) + woff) = pk;
        }
    };

    bf16x8 afn = ldf(0);
    produce(afn, p_s[0]);
    afn = ldf(1);

    int sr = 0, sw = 1;
    for (int t = 0; t < 32; t++) {
        __syncthreads();
        // h A-fragments for PV(t): tiled layout [b][nt64][c][64]
        bf16x8 ah[2][4];
#pragma unroll
        for (int ch = 0; ch < 4; ch++) {
            const unsigned short* hb =
                h_bf + (((size_t)(b * 64 + t * 2 + (ch >> 1))) << 14) + ((ch & 1) << 5) + (q << 3);
#pragma unroll
            for (int cs = 0; cs < 2; cs++)
                ah[cs][ch] = *(const bf16x8*)(hb + ((c0 + cs * 16 + r) << 6));
        }
        if (t < 31) {
            const bf16x8 afc = afn;
            if (t < 30) afn = ldf(t + 2);
            produce(afc, p_s[sw]);
        }
        const unsigned short* pb = p_s[sr];
#pragma unroll
        for (int ch = 0; ch < 4; ch++) {
            bf16x8 bp[4];
#pragma unroll
            for (int ms = 0; ms < 4; ms++) {
                const int idx  = (ch << 2) + q;
                const int phys = (idx & 8) | ((idx ^ r) & 7);
                bp[ms] = *(const bf16x8*)(pb + ((ms * 16 + r) << 7) + (phys << 3));
            }
#pragma unroll
            for (int cs = 0; cs < 2; cs++)
#pragma unroll
                for (int ms = 0; ms < 4; ms++)
                    acc[cs][ms] = __builtin_amdgcn_mfma_f32_16x16x32_bf16(
                        ah[cs][ch], bp[ms], acc[cs][ms], 0, 0, 0);
        }
        sr = sw;
        sw = (sw == 2) ? 0 : sw + 1;
    }

    // ---------------- L reduction ------------------------------------------
#pragma unroll
    for (int ms = 0; ms < 4; ms++) {
        lt[ms] += __shfl_xor(lt[ms], 16);
        lt[ms] += __shfl_xor(lt[ms], 32);
    }
    __syncthreads();
    if (q == 0)
#pragma unroll
        for (int ms = 0; ms < 4; ms++) red_l[w][ms * 16 + r] = lt[ms];
    __syncthreads();
    if (tid < 64) {
        float L = 0.f;
#pragma unroll
        for (int ww = 0; ww < 8; ww++) L += red_l[ww][tid];
        sLi[tid] = 1.f / L;
    }
    __syncthreads();

    // ---------------- epilogue: (gamma/L) * O + x (nontemporal) ------------
    const float gm = gamma[0];
#pragma unroll
    for (int cs = 0; cs < 2; cs++) {
#pragma unroll
        for (int ms = 0; ms < 4; ms++) {
            const float gl = gm * sLi[ms * 16 + r];
#pragma unroll
            for (int reg = 0; reg < 4; reg++) {
                const int c = c0 + cs * 16 + q * 4 + reg;
                const size_t a = (((size_t)b * 256 + c) << 12) + m0 + ms * 16 + r;
                const float xv = __builtin_nontemporal_load(x + a);
                __builtin_nontemporal_store(gl * acc[cs][ms][reg] + xv, out + a);
            }
        }
    }
}

// ------------------------------------------------------------------- launch
extern "C" void kernel_launch(void* const* d_in, const int* in_sizes, int n_in,
                              void* d_out, int out_size, void* d_ws, size_t ws_size,
                              hipStream_t stream) {
    const float* x     = (const float*)d_in[0];
    const float* Wq    = (const float*)d_in[1];
    const float* Wk    = (const float*)d_in[2];
    const float* Wv    = (const float*)d_in[3];
    const float* gamma = (const float*)d_in[4];
    float* out = (float*)d_out;

    char* ws = (char*)d_ws;
    unsigned short* f_t  = (unsigned short*)ws;                        // 2 MB
    unsigned short* g_t  = (unsigned short*)(ws + (2u << 20));         // 2 MB
    unsigned short* h_bf = (unsigned short*)(ws + (4u << 20));         // 16 MB
    float*          ng   = (float*)(ws + (20u << 20));                 // 128 KB
    float*          pmx  = (float*)(ws + (20u << 20) + (1u << 17));    // 8 KB
    unsigned short* wq   = (unsigned short*)(ws + (21u << 20));        // 16 KB
    unsigned short* wk   = wq + 8192;                                  // 16 KB
    unsigned short* wv   = wk + 8192;                                  // 128 KB

    wconv_kernel<<<dim3(320), 256, 0, stream>>>(Wq, Wk, Wv, wq, wk, wv);
    producer_kernel<<<dim3(512), 256, 0, stream>>>(x, wq, wk, wv, f_t, g_t, h_bf, ng, pmx);
    attn_kernel<<<dim3(512), 512, 0, stream>>>(f_t, g_t, h_bf, x, gamma, ng, pmx, out);
}